// Round 2
// baseline (1070.194 us; speedup 1.0000x reference)
//
#include <hip/hip_runtime.h>

typedef _Float16 half8  __attribute__((ext_vector_type(8)));
typedef _Float16 half4v __attribute__((ext_vector_type(4)));
typedef float    floatx4 __attribute__((ext_vector_type(4)));

#define DEVINL __device__ __forceinline__

// async global->LDS, 16B per lane; LDS dest = wave-uniform base + lane*16
DEVINL void async_cp16(const void* g, void* l){
  __builtin_amdgcn_global_load_lds(
      (const __attribute__((address_space(1))) void*)g,
      (__attribute__((address_space(3))) void*)l,
      16, 0, 0);
}

DEVINL float wred64(float x){
  #pragma unroll
  for (int m = 32; m; m >>= 1) x += __shfl_xor(x, m, 64);
  return x;
}

// ---------------------------------------------------------------------------
// Backbone GEMM: C(f16) = relu(A(f32, MxK) @ B + bias), B pre-packed f16 BT(NxK).
// A staged to LDS as f32 via global_load_lds with XOR unit-swizzle
// (phys_unit = logical_unit ^ (row&7)) so fragment reads are 2-way (free).
// 128x128 tile, BK=32, 4 waves 2x2, mfma_f32_16x16x32_f16.
// ---------------------------------------------------------------------------
__global__ __launch_bounds__(256) void k_gemm_bb(
    const float* __restrict__ A, const _Float16* __restrict__ BT,
    const float* __restrict__ bias, _Float16* __restrict__ C,
    int M, int K, int lda)
{
  constexpr int BM = 128, BN = 128, BK = 32;
  __shared__ alignas(16) float    As[BM * BK];   // 16 KB, unit-swizzled rows
  __shared__ alignas(16) _Float16 Bs[BN * BK];   // 8 KB
  const int tid = threadIdx.x, wid = tid >> 6, lane = tid & 63;
  const int bm = blockIdx.x, bn = blockIdx.y;

  // A staging: 4 chunks/wave, 8 rows x 8 units(16B) each
  const float* aSrc[4]; float* aDst[4];
  const int uSw = (lane & 7) ^ ((lane >> 3) & 7);  // logical unit for this lane
  #pragma unroll
  for (int c = 0; c < 4; c++){
    int rloc = wid * 32 + c * 8 + (lane >> 3);
    int r = min(bm * BM + rloc, M - 1);
    aSrc[c] = A + (size_t)r * lda + uSw * 4;
    aDst[c] = &As[(wid * 32 + c * 8) * BK];
  }
  // B staging: 2 chunks/wave, 16 rows x 32 f16 each
  const _Float16* bSrc[2]; _Float16* bDst[2];
  #pragma unroll
  for (int s = 0; s < 2; s++){
    int rb = bn * BN + (wid * 2 + s) * 16 + (lane >> 2);
    bSrc[s] = BT + (size_t)rb * K + (lane & 3) * 8;
    bDst[s] = &Bs[(wid * 2 + s) * 16 * BK];
  }

  floatx4 acc[4][4];
  #pragma unroll
  for (int mt = 0; mt < 4; mt++)
    #pragma unroll
    for (int nt = 0; nt < 4; nt++) acc[mt][nt] = {0.f, 0.f, 0.f, 0.f};

  const int arow0 = (wid >> 1) * 64 + (lane & 15);
  const int g2 = (lane >> 4) * 2;
  const int boff = ((wid & 1) * 64 + (lane & 15)) * BK + (lane >> 4) * 8;

  for (int k0 = 0; k0 < K; k0 += BK){
    __syncthreads();
    #pragma unroll
    for (int c = 0; c < 4; c++) async_cp16(aSrc[c] + k0, aDst[c]);
    #pragma unroll
    for (int s = 0; s < 2; s++) async_cp16(bSrc[s] + k0, bDst[s]);
    __syncthreads();
    half8 af[4], bf[4];
    #pragma unroll
    for (int mt = 0; mt < 4; mt++){
      int arow = arow0 + mt * 16;
      int a7 = arow & 7;
      floatx4 lo = *(const floatx4*)&As[arow * BK + ((g2    ) ^ a7) * 4];
      floatx4 hi = *(const floatx4*)&As[arow * BK + ((g2 + 1) ^ a7) * 4];
      #pragma unroll
      for (int j = 0; j < 4; j++){ af[mt][j] = (_Float16)lo[j]; af[mt][4+j] = (_Float16)hi[j]; }
    }
    #pragma unroll
    for (int nt = 0; nt < 4; nt++) bf[nt] = *(const half8*)&Bs[boff + nt * 16 * BK];
    #pragma unroll
    for (int mt = 0; mt < 4; mt++)
      #pragma unroll
      for (int nt = 0; nt < 4; nt++)
        acc[mt][nt] = __builtin_amdgcn_mfma_f32_16x16x32_f16(af[mt], bf[nt], acc[mt][nt], 0, 0, 0);
  }

  // C/D layout: col = lane&15, row = (lane>>4)*4 + i
  const int colLocal = (wid & 1) * 64 + (lane & 15);
  const int rowLocal = (wid >> 1) * 64 + (lane >> 4) * 4;
  #pragma unroll
  for (int nt = 0; nt < 4; nt++){
    int col = bn * BN + colLocal + nt * 16;
    float b = bias[col];
    #pragma unroll
    for (int mt = 0; mt < 4; mt++){
      int r0 = bm * BM + rowLocal + mt * 16;
      #pragma unroll
      for (int i = 0; i < 4; i++){
        int r = r0 + i;
        if (r < M){
          float v = fmaxf(acc[mt][nt][i] + b, 0.f);
          C[(size_t)r * 256 + col] = (_Float16)v;
        }
      }
    }
  }
}

// ---------------------------------------------------------------------------
// f16 GEMM: C = A(f16, Mpad x 256) @ B + bias, BT(N x 256) pre-packed f16.
// SPLIT: N=512, cols [0,256)->C0, [256,512)->C1.  VERTC: +verts@vertW rank-3.
// ---------------------------------------------------------------------------
template<bool RELU, bool SPLIT, bool VERTC>
__global__ __launch_bounds__(256) void k_gemm_h(
    const _Float16* __restrict__ A, int Mstore, int Vreal,
    const _Float16* __restrict__ BT,
    const float* __restrict__ bias0, const float* __restrict__ bias1,
    const float* __restrict__ vertW, const float* __restrict__ verts,
    _Float16* __restrict__ C0, _Float16* __restrict__ C1)
{
  constexpr int BM = 128, BN = 128, BK = 32, K = 256;
  __shared__ alignas(16) _Float16 As[BM * BK];
  __shared__ alignas(16) _Float16 Bs[BN * BK];
  const int tid = threadIdx.x, wid = tid >> 6, lane = tid & 63;
  const int bm = blockIdx.x, bn = blockIdx.y;
  const int sub = lane >> 2, kof = (lane & 3) * 8;

  const _Float16* aSrc[2]; _Float16* aDst[2];
  const _Float16* bSrc[2]; _Float16* bDst[2];
  #pragma unroll
  for (int s = 0; s < 2; s++){
    int r = bm * BM + (wid * 2 + s) * 16 + sub;
    aSrc[s] = A + (size_t)r * K + kof;
    aDst[s] = &As[(wid * 2 + s) * 512];
    int rb = bn * BN + (wid * 2 + s) * 16 + sub;
    bSrc[s] = BT + (size_t)rb * K + kof;
    bDst[s] = &Bs[(wid * 2 + s) * 512];
  }

  floatx4 acc[4][4];
  #pragma unroll
  for (int mt = 0; mt < 4; mt++)
    #pragma unroll
    for (int nt = 0; nt < 4; nt++) acc[mt][nt] = {0.f, 0.f, 0.f, 0.f};

  const int aoff = ((wid >> 1) * 64 + (lane & 15)) * BK + (lane >> 4) * 8;
  const int boff = ((wid & 1) * 64 + (lane & 15)) * BK + (lane >> 4) * 8;

  for (int k0 = 0; k0 < K; k0 += BK){
    __syncthreads();
    async_cp16(aSrc[0] + k0, aDst[0]);
    async_cp16(aSrc[1] + k0, aDst[1]);
    async_cp16(bSrc[0] + k0, bDst[0]);
    async_cp16(bSrc[1] + k0, bDst[1]);
    __syncthreads();
    half8 af[4], bf[4];
    #pragma unroll
    for (int mt = 0; mt < 4; mt++) af[mt] = *(const half8*)&As[aoff + mt * 16 * BK];
    #pragma unroll
    for (int nt = 0; nt < 4; nt++) bf[nt] = *(const half8*)&Bs[boff + nt * 16 * BK];
    #pragma unroll
    for (int mt = 0; mt < 4; mt++)
      #pragma unroll
      for (int nt = 0; nt < 4; nt++)
        acc[mt][nt] = __builtin_amdgcn_mfma_f32_16x16x32_f16(af[mt], bf[nt], acc[mt][nt], 0, 0, 0);
  }

  const int colLocal = (wid & 1) * 64 + (lane & 15);
  const int rowLocal = (wid >> 1) * 64 + (lane >> 4) * 4;
  #pragma unroll
  for (int nt = 0; nt < 4; nt++){
    int g = bn * BN + colLocal + nt * 16;
    _Float16* Cp = C0;
    const float* bp = bias0;
    int col = g;
    if (SPLIT && g >= 256){ Cp = C1; bp = bias1; col = g - 256; }
    float b = bp[col];
    float w0 = 0.f, w1 = 0.f, w2 = 0.f;
    if (VERTC){ w0 = vertW[g*3+0]; w1 = vertW[g*3+1]; w2 = vertW[g*3+2]; }
    #pragma unroll
    for (int mt = 0; mt < 4; mt++){
      int r0 = bm * BM + rowLocal + mt * 16;
      #pragma unroll
      for (int i = 0; i < 4; i++){
        int r = r0 + i;
        if (r < Mstore){
          float v = acc[mt][nt][i] + b;
          if (VERTC){
            int vr = min(r, Vreal - 1);
            v += verts[vr*3+0] * w0 + verts[vr*3+1] * w1 + verts[vr*3+2] * w2;
          }
          if (RELU) v = fmaxf(v, 0.f);
          Cp[(size_t)r * 256 + col] = (_Float16)v;
        }
      }
    }
  }
}

// ---------------------------------------------------------------------------
__global__ __launch_bounds__(256) void k_fill(const int* __restrict__ e, int E,
                                              int* __restrict__ cnt, int* __restrict__ adj){
  int t = blockIdx.x * 256 + threadIdx.x;
  if (t >= E) return;
  int i = e[t*2], j = e[t*2+1];
  int s = atomicAdd(&cnt[i], 1); if (s < 64) adj[(size_t)i*64 + s] = j;
  int q = atomicAdd(&cnt[j], 1); if (q < 64) adj[(size_t)j*64 + q] = i;
}

// ---------------------------------------------------------------------------
// Weight repack f32 -> f16 BT(NxK) layouts + vert-correction weights (f32)
// ---------------------------------------------------------------------------
__global__ __launch_bounds__(256) void k_pack(
    const float* __restrict__ Wb,
    const float* __restrict__ W0_0, const float* __restrict__ W1_0,
    const float* __restrict__ gW0,  const float* __restrict__ gW1,
    const float* __restrict__ A1,
    _Float16* __restrict__ WbT, _Float16* __restrict__ convB,
    _Float16* __restrict__ A1T, float* __restrict__ vertW)
{
  const int S1 = 256*3840, S2 = 10*512*256, S3 = 256*256, S4 = 512*3;
  int id = blockIdx.x * 256 + threadIdx.x;
  if (id < S1){ int n = id / 3840, k = id % 3840; WbT[id] = (_Float16)Wb[(size_t)k*256 + n]; return; }
  id -= S1;
  if (id < S2){
    int l = id / (512*256); int rem = id % (512*256);
    int r = rem / 256, k = rem % 256;
    const float* W0 = (l == 0) ? W0_0 : gW0 + (size_t)(l-1)*65536;
    const float* W1 = (l == 0) ? W1_0 : gW1 + (size_t)(l-1)*65536;
    convB[id] = (_Float16)((r < 256) ? W0[(size_t)k*256 + r] : W1[(size_t)k*256 + (r-256)]);
    return;
  }
  id -= S2;
  if (id < S3){ int n = id / 256, k = id % 256; A1T[id] = (_Float16)A1[(size_t)k*256 + n]; return; }
  id -= S3;
  if (id < S4){
    int n = id / 3, c = id % 3;
    vertW[id] = (n < 256) ? W0_0[(size_t)(256+c)*256 + n]
                          : W1_0[(size_t)(256+c)*256 + (n-256)];
  }
}

// ---------------------------------------------------------------------------
// Gather: h[v] = relu(out[v] + sum_{u in adj[v]} nbr[u]); one wave per vertex.
// ---------------------------------------------------------------------------
__global__ __launch_bounds__(256) void k_gather(
    const _Float16* __restrict__ outB, const _Float16* __restrict__ nbrB,
    const int* __restrict__ cnt, const int* __restrict__ adj,
    _Float16* __restrict__ h, int V)
{
  int gw = (int)((blockIdx.x * 256 + threadIdx.x) >> 6);
  int lane = threadIdx.x & 63;
  if (gw >= V) return;
  half4v o = ((const half4v*)(outB + (size_t)gw * 256))[lane];
  float a0 = (float)o[0], a1 = (float)o[1], a2 = (float)o[2], a3 = (float)o[3];
  int n = min(cnt[gw], 64);
  const int* ap = adj + (size_t)gw * 64;
  for (int d = 0; d < n; d++){
    int u = ap[d];
    half4v x = ((const half4v*)(nbrB + (size_t)u * 256))[lane];
    a0 += (float)x[0]; a1 += (float)x[1]; a2 += (float)x[2]; a3 += (float)x[3];
  }
  half4v rr;
  rr[0] = (_Float16)fmaxf(a0, 0.f); rr[1] = (_Float16)fmaxf(a1, 0.f);
  rr[2] = (_Float16)fmaxf(a2, 0.f); rr[3] = (_Float16)fmaxf(a3, 0.f);
  ((half4v*)(h + (size_t)gw * 256))[lane] = rr;
}

// ---------------------------------------------------------------------------
// Head: delta_v = h@Wo+bo ; conf = sigmoid(relu(relu(z1@A2+a2)@A3+a3)@A4+a4)
// ---------------------------------------------------------------------------
__global__ __launch_bounds__(1024) void k_head(
    const _Float16* __restrict__ hA, const _Float16* __restrict__ z1,
    const float* __restrict__ Wo, const float* __restrict__ bo,
    const float* __restrict__ A2, const float* __restrict__ a2,
    const float* __restrict__ A3, const float* __restrict__ a3,
    const float* __restrict__ A4, const float* __restrict__ a4,
    float* __restrict__ dOut, int V)
{
  __shared__ float A2s[256 * 64];
  __shared__ float A3s[64 * 32];
  __shared__ float Wos[768];
  __shared__ float zrow[16][256];
  __shared__ float z2s[16][64];
  const int tid = threadIdx.x;
  for (int i = tid; i < 256*64; i += 1024) A2s[i] = A2[i];
  for (int i = tid; i < 64*32;  i += 1024) A3s[i] = A3[i];
  if (tid < 768) Wos[tid] = Wo[tid];
  __syncthreads();
  const int wid = tid >> 6, lane = tid & 63;
  const int v = blockIdx.x * 16 + wid;
  if (v >= V) return;

  // delta_v
  half4v hv = ((const half4v*)(hA + (size_t)v * 256))[lane];
  float hf[4] = { (float)hv[0], (float)hv[1], (float)hv[2], (float)hv[3] };
  float p0 = 0.f, p1 = 0.f, p2 = 0.f;
  int c0 = lane * 4;
  #pragma unroll
  for (int j = 0; j < 4; j++){
    p0 += hf[j] * Wos[(c0+j)*3 + 0];
    p1 += hf[j] * Wos[(c0+j)*3 + 1];
    p2 += hf[j] * Wos[(c0+j)*3 + 2];
  }
  p0 = wred64(p0); p1 = wred64(p1); p2 = wred64(p2);
  if (lane == 0){
    dOut[(size_t)v*3 + 0] = p0 + bo[0];
    dOut[(size_t)v*3 + 1] = p1 + bo[1];
    dOut[(size_t)v*3 + 2] = p2 + bo[2];
  }

  // conf MLP
  half4v zv = ((const half4v*)(z1 + (size_t)v * 256))[lane];
  floatx4 zf; zf[0] = (float)zv[0]; zf[1] = (float)zv[1]; zf[2] = (float)zv[2]; zf[3] = (float)zv[3];
  ((floatx4*)zrow[wid])[lane] = zf;
  __threadfence_block();
  float acc2 = a2[lane];
  #pragma unroll 4
  for (int c = 0; c < 256; c++) acc2 += zrow[wid][c] * A2s[c*64 + lane];
  acc2 = fmaxf(acc2, 0.f);
  z2s[wid][lane] = acc2;
  __threadfence_block();
  int o = lane & 31;
  float acc3 = a3[o];
  #pragma unroll 4
  for (int c = 0; c < 64; c++) acc3 += z2s[wid][c] * A3s[c*32 + o];
  acc3 = fmaxf(acc3, 0.f);
  float p = (lane < 32) ? acc3 * A4[lane] : 0.f;
  p = wred64(p);
  if (lane == 0){
    float s = 1.f / (1.f + expf(-(p + a4[0])));
    dOut[(size_t)V*3 + v] = s;
  }
}

// ---------------------------------------------------------------------------
extern "C" void kernel_launch(void* const* d_in, const int* in_sizes, int n_in,
                              void* d_out, int out_size, void* d_ws, size_t ws_size,
                              hipStream_t stream)
{
  const int V = 20496, E = 61440, F = 3840, Vpad = 20608; // 161*128
  const float* X     = (const float*)d_in[0];
  const float* verts = (const float*)d_in[1];
  const int*   edges = (const int*)d_in[2];
  const float* Wb    = (const float*)d_in[3];
  const float* bb    = (const float*)d_in[4];
  const float* W0_0  = (const float*)d_in[5];
  const float* b0_0  = (const float*)d_in[6];
  const float* W1_0  = (const float*)d_in[7];
  const float* b1_0  = (const float*)d_in[8];
  const float* gW0   = (const float*)d_in[9];
  const float* gb0   = (const float*)d_in[10];
  const float* gW1   = (const float*)d_in[11];
  const float* gb1   = (const float*)d_in[12];
  const float* Wo    = (const float*)d_in[13];
  const float* bo    = (const float*)d_in[14];
  const float* A1    = (const float*)d_in[15];
  const float* a1    = (const float*)d_in[16];
  const float* A2    = (const float*)d_in[17];
  const float* a2    = (const float*)d_in[18];
  const float* A3    = (const float*)d_in[19];
  const float* a3    = (const float*)d_in[20];
  const float* A4    = (const float*)d_in[21];
  const float* a4    = (const float*)d_in[22];

  char* w = (char*)d_ws;
  const size_t SA = (size_t)Vpad * 256 * 2;   // one Vpad x 256 f16 buffer
  _Float16* hA    = (_Float16*)(w);
  _Float16* outB  = (_Float16*)(w + SA);
  _Float16* nbrB  = (_Float16*)(w + 2*SA);
  _Float16* z1    = (_Float16*)(w + 3*SA);
  size_t off = 4 * SA;
  _Float16* WbT   = (_Float16*)(w + off); off += (size_t)256*3840*2;
  _Float16* convB = (_Float16*)(w + off); off += (size_t)10*512*256*2;
  _Float16* A1T   = (_Float16*)(w + off); off += (size_t)256*256*2;
  float*    vertW = (float*)(w + off);    off += (size_t)512*3*4;
  int*      cnt   = (int*)(w + off);      off += (size_t)V*4;
  int*      adj   = (int*)(w + off);      // V*64*4

  hipMemsetAsync(cnt, 0, (size_t)V*4, stream);
  hipMemsetAsync(hA + (size_t)V*256, 0, (size_t)(Vpad - V)*256*2, stream);  // zero pad rows

  k_fill<<<dim3((E + 255)/256), dim3(256), 0, stream>>>(edges, E, cnt, adj);
  {
    const int total = 256*3840 + 10*512*256 + 256*256 + 512*3;
    k_pack<<<dim3((total + 255)/256), dim3(256), 0, stream>>>(
        Wb, W0_0, W1_0, gW0, gW1, A1, WbT, convB, A1T, vertW);
  }

  // backbone: hA = relu(X @ Wb + bb)
  k_gemm_bb<<<dim3(161, 2), dim3(256), 0, stream>>>(X, WbT, bb, hA, V, F, F);

  for (int l = 0; l < 10; l++){
    const float* bp0 = l ? gb0 + (size_t)(l-1)*256 : b0_0;
    const float* bp1 = l ? gb1 + (size_t)(l-1)*256 : b1_0;
    const _Float16* Bt = convB + (size_t)l * 512 * 256;
    if (l == 0)
      k_gemm_h<false, true, true><<<dim3(161, 4), dim3(256), 0, stream>>>(
          hA, Vpad, V, Bt, bp0, bp1, vertW, verts, outB, nbrB);
    else
      k_gemm_h<false, true, false><<<dim3(161, 4), dim3(256), 0, stream>>>(
          hA, Vpad, V, Bt, bp0, bp1, nullptr, nullptr, outB, nbrB);
    k_gather<<<dim3(5124), dim3(256), 0, stream>>>(outB, nbrB, cnt, adj, hA, V);
  }

  // z1 = relu(h @ A1 + a1)
  k_gemm_h<true, false, false><<<dim3(161, 2), dim3(256), 0, stream>>>(
      hA, Vpad, V, A1T, a1, nullptr, nullptr, nullptr, z1, nullptr);

  k_head<<<dim3(V/16), dim3(1024), 0, stream>>>(
      hA, z1, Wo, bo, A2, a2, A3, a3, A4, a4, (float*)d_out, V);
}

// Round 3
// 991.594 us; speedup vs baseline: 1.0793x; 1.0793x over previous
//
#include <hip/hip_runtime.h>

typedef _Float16 half8  __attribute__((ext_vector_type(8)));
typedef _Float16 half4v __attribute__((ext_vector_type(4)));
typedef float    floatx4 __attribute__((ext_vector_type(4)));

#define DEVINL __device__ __forceinline__

// async global->LDS, 16B per lane; LDS dest = wave-uniform base + lane*16
DEVINL void async_cp16(const void* g, void* l){
  __builtin_amdgcn_global_load_lds(
      (const __attribute__((address_space(1))) void*)g,
      (__attribute__((address_space(3))) void*)l,
      16, 0, 0);
}

DEVINL float wred64(float x){
  #pragma unroll
  for (int m = 32; m; m >>= 1) x += __shfl_xor(x, m, 64);
  return x;
}

// ---------------------------------------------------------------------------
// Backbone GEMM, split-K: P[z] = A(f32 slice)@B(slice), f32 partials, no bias.
// 128x128 tile, BK=32, 4 waves 2x2. A f32 staged via global_load_lds with XOR
// unit swizzle; B f16 likewise (units of 16B, phys = logical ^ (row&3)).
// ---------------------------------------------------------------------------
__global__ __launch_bounds__(256) void k_gemm_bb(
    const float* __restrict__ A, const _Float16* __restrict__ BT,
    float* __restrict__ P, int M, int Mpad, int K, int lda, int kChunk)
{
  constexpr int BM = 128, BK = 32;
  __shared__ alignas(16) float    As[BM * BK];   // 16 KB
  __shared__ alignas(16) _Float16 Bs[BM * BK];   // 8 KB
  const int tid = threadIdx.x, wid = tid >> 6, lane = tid & 63;
  const int bm = blockIdx.x, bn = blockIdx.y, bz = blockIdx.z;
  const int kbeg = bz * kChunk, kend = kbeg + kChunk;

  // A staging: 4 chunks/wave, 8 rows x 8 units(16B); phys unit lane&7 holds
  // logical (lane&7)^(row&7)
  const float* aSrc[4]; float* aDst[4];
  const int uSwA = (lane & 7) ^ ((lane >> 3) & 7);
  #pragma unroll
  for (int c = 0; c < 4; c++){
    int rloc = wid * 32 + c * 8 + (lane >> 3);
    int r = min(bm * BM + rloc, M - 1);
    aSrc[c] = A + (size_t)r * lda + uSwA * 4;
    aDst[c] = &As[(wid * 32 + c * 8) * BK];
  }
  // B staging: 2 chunks/wave, 16 rows x 4 units(16B); phys lane&3 holds
  // logical (lane&3)^(row&3)
  const _Float16* bSrc[2]; _Float16* bDst[2];
  const int uSwB = (lane & 3) ^ ((lane >> 2) & 3);
  #pragma unroll
  for (int s = 0; s < 2; s++){
    int rb = bn * BM + (wid * 2 + s) * 16 + (lane >> 2);
    bSrc[s] = BT + (size_t)rb * K + uSwB * 8;
    bDst[s] = &Bs[(wid * 2 + s) * 16 * BK];
  }

  floatx4 acc[4][4];
  #pragma unroll
  for (int mt = 0; mt < 4; mt++)
    #pragma unroll
    for (int nt = 0; nt < 4; nt++) acc[mt][nt] = {0.f, 0.f, 0.f, 0.f};

  const int arow0 = (wid >> 1) * 64 + (lane & 15);
  const int g2 = (lane >> 4) * 2;
  const int a7 = lane & 7;
  const int brow0 = (wid & 1) * 64 + (lane & 15);
  const int ub = (lane >> 4) ^ (lane & 3);

  for (int k0 = kbeg; k0 < kend; k0 += BK){
    __syncthreads();
    #pragma unroll
    for (int c = 0; c < 4; c++) async_cp16(aSrc[c] + k0, aDst[c]);
    #pragma unroll
    for (int s = 0; s < 2; s++) async_cp16(bSrc[s] + k0, bDst[s]);
    __syncthreads();
    half8 af[4], bf[4];
    #pragma unroll
    for (int mt = 0; mt < 4; mt++){
      int arow = arow0 + mt * 16;
      floatx4 lo = *(const floatx4*)&As[arow * BK + ((g2    ) ^ a7) * 4];
      floatx4 hi = *(const floatx4*)&As[arow * BK + ((g2 + 1) ^ a7) * 4];
      #pragma unroll
      for (int j = 0; j < 4; j++){ af[mt][j] = (_Float16)lo[j]; af[mt][4+j] = (_Float16)hi[j]; }
    }
    #pragma unroll
    for (int nt = 0; nt < 4; nt++)
      bf[nt] = *(const half8*)&Bs[(brow0 + nt * 16) * BK + ub * 8];
    #pragma unroll
    for (int mt = 0; mt < 4; mt++)
      #pragma unroll
      for (int nt = 0; nt < 4; nt++)
        acc[mt][nt] = __builtin_amdgcn_mfma_f32_16x16x32_f16(af[mt], bf[nt], acc[mt][nt], 0, 0, 0);
  }

  // C/D layout: col = lane&15, row = (lane>>4)*4 + i
  const int colLocal = (wid & 1) * 64 + (lane & 15);
  const int rowLocal = (wid >> 1) * 64 + (lane >> 4) * 4;
  float* Pz = P + (size_t)bz * Mpad * 256;
  #pragma unroll
  for (int nt = 0; nt < 4; nt++){
    int col = bn * BM + colLocal + nt * 16;
    #pragma unroll
    for (int mt = 0; mt < 4; mt++){
      int r0 = bm * BM + rowLocal + mt * 16;
      #pragma unroll
      for (int i = 0; i < 4; i++)
        Pz[(size_t)(r0 + i) * 256 + col] = acc[mt][nt][i];
    }
  }
}

// ---------------------------------------------------------------------------
// Reduce split-K partials: hA = relu(sum_z P[z] + bias), f16; pad rows -> 0.
// ---------------------------------------------------------------------------
__global__ __launch_bounds__(256) void k_reduce(
    const float* __restrict__ P, const float* __restrict__ bias,
    _Float16* __restrict__ hA, int V, int Mpad)
{
  int idx = blockIdx.x * 256 + threadIdx.x;  // quad index
  int base = idx * 4;
  int r = base >> 8, c = base & 255;
  const size_t stride = (size_t)Mpad * 256;
  const float* p = P + (size_t)r * 256 + c;
  floatx4 s0 = *(const floatx4*)(p);
  floatx4 s1 = *(const floatx4*)(p + stride);
  floatx4 s2 = *(const floatx4*)(p + 2 * stride);
  floatx4 s3 = *(const floatx4*)(p + 3 * stride);
  floatx4 b = *(const floatx4*)(bias + c);
  half4v o;
  if (r < V){
    #pragma unroll
    for (int e = 0; e < 4; e++)
      o[e] = (_Float16)fmaxf(s0[e] + s1[e] + s2[e] + s3[e] + b[e], 0.f);
  } else {
    #pragma unroll
    for (int e = 0; e < 4; e++) o[e] = (_Float16)0.f;
  }
  *(half4v*)(hA + (size_t)r * 256 + c) = o;
}

// ---------------------------------------------------------------------------
// Conv/z1 GEMM: barrier-free streamer. Weights pre-packed in MFMA fragment
// order: frag id r = n16*8 + j (n16 = n>>4 within the N-slice, j = k>>5),
// element (lane, e): n = n16*16 + (lane&15), k = j*32 + (lane>>4)*8 + e.
// Block: 128m x 128n, 4 waves (2x2), B tile = 64KB LDS staged once.
// A fragments read directly from global (f16, LLC-resident).
// ---------------------------------------------------------------------------
template<bool RELU, bool SPLIT, bool VERTC>
__global__ __launch_bounds__(256) void k_conv(
    const _Float16* __restrict__ A,       // Mpad x 256
    const _Float16* __restrict__ BTfrag,  // fragment-packed slice base
    const float* __restrict__ bias0, const float* __restrict__ bias1,
    const float* __restrict__ vertW, const float* __restrict__ verts,
    _Float16* __restrict__ C0, _Float16* __restrict__ C1, int Vreal)
{
  __shared__ alignas(16) _Float16 Bs[32768];  // 64 KB
  const int tid = threadIdx.x, wid = tid >> 6, lane = tid & 63;
  const int bm = blockIdx.x, bn = blockIdx.y;

  const _Float16* src = BTfrag + (size_t)bn * 32768;
  #pragma unroll
  for (int jj = 0; jj < 16; jj++){
    int e = (jj * 256 + tid) * 8;
    *(half8*)&Bs[e] = *(const half8*)&src[e];
  }
  __syncthreads();

  const _Float16* Arow[4];
  #pragma unroll
  for (int mt = 0; mt < 4; mt++)
    Arow[mt] = A + (size_t)(bm * 128 + (wid >> 1) * 64 + mt * 16 + (lane & 15)) * 256
                 + (lane >> 4) * 8;
  const int nbase = (wid & 1) * 4;

  floatx4 acc[4][4];
  #pragma unroll
  for (int mt = 0; mt < 4; mt++)
    #pragma unroll
    for (int nt = 0; nt < 4; nt++) acc[mt][nt] = {0.f, 0.f, 0.f, 0.f};

  #pragma unroll
  for (int j = 0; j < 8; j++){
    half8 af[4], bf[4];
    #pragma unroll
    for (int mt = 0; mt < 4; mt++) af[mt] = *(const half8*)(Arow[mt] + j * 32);
    #pragma unroll
    for (int nt = 0; nt < 4; nt++)
      bf[nt] = *(const half8*)&Bs[(((nbase + nt) * 8 + j) * 64 + lane) * 8];
    #pragma unroll
    for (int mt = 0; mt < 4; mt++)
      #pragma unroll
      for (int nt = 0; nt < 4; nt++)
        acc[mt][nt] = __builtin_amdgcn_mfma_f32_16x16x32_f16(af[mt], bf[nt], acc[mt][nt], 0, 0, 0);
  }

  const int colLocal = (wid & 1) * 64 + (lane & 15);
  const int rowLocal = (wid >> 1) * 64 + (lane >> 4) * 4;
  #pragma unroll
  for (int nt = 0; nt < 4; nt++){
    int g = bn * 128 + colLocal + nt * 16;
    _Float16* Cp = C0;
    const float* bp = bias0;
    int col = g;
    if (SPLIT && g >= 256){ Cp = C1; bp = bias1; col = g - 256; }
    float b = bp[col];
    float w0 = 0.f, w1 = 0.f, w2 = 0.f;
    if (VERTC){ w0 = vertW[g*3+0]; w1 = vertW[g*3+1]; w2 = vertW[g*3+2]; }
    #pragma unroll
    for (int mt = 0; mt < 4; mt++){
      int r0 = bm * 128 + rowLocal + mt * 16;
      #pragma unroll
      for (int i = 0; i < 4; i++){
        int r = r0 + i;
        float v = acc[mt][nt][i] + b;
        if (VERTC){
          int vr = min(r, Vreal - 1);
          v += verts[vr*3+0] * w0 + verts[vr*3+1] * w1 + verts[vr*3+2] * w2;
        }
        if (RELU) v = fmaxf(v, 0.f);
        Cp[(size_t)r * 256 + col] = (_Float16)v;
      }
    }
  }
}

// ---------------------------------------------------------------------------
__global__ __launch_bounds__(256) void k_fill(const int* __restrict__ e, int E,
                                              int* __restrict__ cnt, int* __restrict__ adj){
  int t = blockIdx.x * 256 + threadIdx.x;
  if (t >= E) return;
  int i = e[t*2], j = e[t*2+1];
  int s = atomicAdd(&cnt[i], 1); if (s < 64) adj[(size_t)i*64 + s] = j;
  int q = atomicAdd(&cnt[j], 1); if (q < 64) adj[(size_t)j*64 + q] = i;
}

// ---------------------------------------------------------------------------
// WbT transpose (f32 KxN -> f16 NxK) via LDS 64x64 tiles, fully coalesced.
// ---------------------------------------------------------------------------
__global__ __launch_bounds__(256) void k_trans_bb(
    const float* __restrict__ Wb, _Float16* __restrict__ WbT)
{
  __shared__ float T[64][65];
  const int k0 = blockIdx.x * 64, n0 = blockIdx.y * 64;
  const int tr = threadIdx.x >> 6, tc = threadIdx.x & 63;
  #pragma unroll
  for (int i = 0; i < 16; i++){
    int rr = i * 4 + tr;
    T[rr][tc] = Wb[(size_t)(k0 + rr) * 256 + n0 + tc];
  }
  __syncthreads();
  #pragma unroll
  for (int i = 0; i < 16; i++){
    int rr = i * 4 + tr;
    WbT[(size_t)(n0 + rr) * 3840 + k0 + tc] = (_Float16)T[tc][rr];
  }
}

// ---------------------------------------------------------------------------
// Fragment-order weight packer: one wave per fragment row (L,n16,j).
// convB: 10 layers x 512x256; A1T: 256x256. Tail block: vertW.
// ---------------------------------------------------------------------------
__global__ __launch_bounds__(256) void k_pack_frag(
    const float* __restrict__ W0_0, const float* __restrict__ W1_0,
    const float* __restrict__ gW0,  const float* __restrict__ gW1,
    const float* __restrict__ A1,
    _Float16* __restrict__ convB, _Float16* __restrict__ A1T,
    float* __restrict__ vertW)
{
  if (blockIdx.x == 672){
    for (int i = threadIdx.x; i < 1536; i += 256){
      int n = i / 3, c = i % 3;
      vertW[i] = (n < 256) ? W0_0[(size_t)(256 + c) * 256 + n]
                           : W1_0[(size_t)(256 + c) * 256 + (n - 256)];
    }
    return;
  }
  const int gw = blockIdx.x * 4 + (threadIdx.x >> 6);
  const int lane = threadIdx.x & 63;
  if (gw < 2560){
    int L = gw >> 8;
    int r = gw & 255;
    int n = (r >> 3) * 16 + (lane & 15);
    int k = (r & 7) * 32 + (lane >> 4) * 8;
    const float* W0 = L ? gW0 + (size_t)(L - 1) * 65536 : W0_0;
    const float* W1 = L ? gW1 + (size_t)(L - 1) * 65536 : W1_0;
    const float* Wsel = (n < 256) ? W0 : W1;
    int nn = n & 255;
    half8 v;
    #pragma unroll
    for (int e = 0; e < 8; e++) v[e] = (_Float16)Wsel[(size_t)(k + e) * 256 + nn];
    *(half8*)&convB[(size_t)L * 131072 + (size_t)r * 512 + lane * 8] = v;
  } else {
    int r = gw - 2560;
    int n = (r >> 3) * 16 + (lane & 15);
    int k = (r & 7) * 32 + (lane >> 4) * 8;
    half8 v;
    #pragma unroll
    for (int e = 0; e < 8; e++) v[e] = (_Float16)A1[(size_t)(k + e) * 256 + n];
    *(half8*)&A1T[(size_t)r * 512 + lane * 8] = v;
  }
}

// ---------------------------------------------------------------------------
// Gather: h[v] = relu(out[v] + sum_{u in adj[v]} nbr[u]); one wave per vertex.
// ---------------------------------------------------------------------------
__global__ __launch_bounds__(256) void k_gather(
    const _Float16* __restrict__ outB, const _Float16* __restrict__ nbrB,
    const int* __restrict__ cnt, const int* __restrict__ adj,
    _Float16* __restrict__ h, int V)
{
  int gw = (int)((blockIdx.x * 256 + threadIdx.x) >> 6);
  int lane = threadIdx.x & 63;
  if (gw >= V) return;
  half4v o = ((const half4v*)(outB + (size_t)gw * 256))[lane];
  float a0 = (float)o[0], a1 = (float)o[1], a2 = (float)o[2], a3 = (float)o[3];
  int n = min(cnt[gw], 64);
  const int* ap = adj + (size_t)gw * 64;
  int d = 0;
  for (; d + 1 < n; d += 2){
    int u0 = ap[d], u1 = ap[d+1];
    half4v x = ((const half4v*)(nbrB + (size_t)u0 * 256))[lane];
    half4v y = ((const half4v*)(nbrB + (size_t)u1 * 256))[lane];
    a0 += (float)x[0] + (float)y[0]; a1 += (float)x[1] + (float)y[1];
    a2 += (float)x[2] + (float)y[2]; a3 += (float)x[3] + (float)y[3];
  }
  if (d < n){
    int u = ap[d];
    half4v x = ((const half4v*)(nbrB + (size_t)u * 256))[lane];
    a0 += (float)x[0]; a1 += (float)x[1]; a2 += (float)x[2]; a3 += (float)x[3];
  }
  half4v rr;
  rr[0] = (_Float16)fmaxf(a0, 0.f); rr[1] = (_Float16)fmaxf(a1, 0.f);
  rr[2] = (_Float16)fmaxf(a2, 0.f); rr[3] = (_Float16)fmaxf(a3, 0.f);
  ((half4v*)(h + (size_t)gw * 256))[lane] = rr;
}

// ---------------------------------------------------------------------------
// Head: delta_v = h@Wo+bo ; conf = sigmoid(relu(relu(z1@A2+a2)@A3+a3)@A4+a4)
// ---------------------------------------------------------------------------
__global__ __launch_bounds__(1024) void k_head(
    const _Float16* __restrict__ hA, const _Float16* __restrict__ z1,
    const float* __restrict__ Wo, const float* __restrict__ bo,
    const float* __restrict__ A2, const float* __restrict__ a2,
    const float* __restrict__ A3, const float* __restrict__ a3,
    const float* __restrict__ A4, const float* __restrict__ a4,
    float* __restrict__ dOut, int V)
{
  __shared__ float A2s[256 * 64];
  __shared__ float A3s[64 * 32];
  __shared__ float Wos[768];
  __shared__ float zrow[16][256];
  __shared__ float z2s[16][64];
  const int tid = threadIdx.x;
  for (int i = tid; i < 256*64; i += 1024) A2s[i] = A2[i];
  for (int i = tid; i < 64*32;  i += 1024) A3s[i] = A3[i];
  if (tid < 768) Wos[tid] = Wo[tid];
  __syncthreads();
  const int wid = tid >> 6, lane = tid & 63;
  const int v = blockIdx.x * 16 + wid;
  if (v >= V) return;

  half4v hv = ((const half4v*)(hA + (size_t)v * 256))[lane];
  float hf[4] = { (float)hv[0], (float)hv[1], (float)hv[2], (float)hv[3] };
  float p0 = 0.f, p1 = 0.f, p2 = 0.f;
  int c0 = lane * 4;
  #pragma unroll
  for (int j = 0; j < 4; j++){
    p0 += hf[j] * Wos[(c0+j)*3 + 0];
    p1 += hf[j] * Wos[(c0+j)*3 + 1];
    p2 += hf[j] * Wos[(c0+j)*3 + 2];
  }
  p0 = wred64(p0); p1 = wred64(p1); p2 = wred64(p2);
  if (lane == 0){
    dOut[(size_t)v*3 + 0] = p0 + bo[0];
    dOut[(size_t)v*3 + 1] = p1 + bo[1];
    dOut[(size_t)v*3 + 2] = p2 + bo[2];
  }

  half4v zv = ((const half4v*)(z1 + (size_t)v * 256))[lane];
  floatx4 zf; zf[0] = (float)zv[0]; zf[1] = (float)zv[1]; zf[2] = (float)zv[2]; zf[3] = (float)zv[3];
  ((floatx4*)zrow[wid])[lane] = zf;
  __threadfence_block();
  float acc2 = a2[lane];
  #pragma unroll 4
  for (int c = 0; c < 256; c++) acc2 += zrow[wid][c] * A2s[c*64 + lane];
  acc2 = fmaxf(acc2, 0.f);
  z2s[wid][lane] = acc2;
  __threadfence_block();
  int o = lane & 31;
  float acc3 = a3[o];
  #pragma unroll 4
  for (int c = 0; c < 64; c++) acc3 += z2s[wid][c] * A3s[c*32 + o];
  acc3 = fmaxf(acc3, 0.f);
  float p = (lane < 32) ? acc3 * A4[lane] : 0.f;
  p = wred64(p);
  if (lane == 0){
    float s = 1.f / (1.f + expf(-(p + a4[0])));
    dOut[(size_t)V*3 + v] = s;
  }
}

// ---------------------------------------------------------------------------
extern "C" void kernel_launch(void* const* d_in, const int* in_sizes, int n_in,
                              void* d_out, int out_size, void* d_ws, size_t ws_size,
                              hipStream_t stream)
{
  const int V = 20496, E = 61440, F = 3840, Vpad = 20608; // 161*128
  const float* X     = (const float*)d_in[0];
  const float* verts = (const float*)d_in[1];
  const int*   edges = (const int*)d_in[2];
  const float* Wb    = (const float*)d_in[3];
  const float* bbias = (const float*)d_in[4];
  const float* W0_0  = (const float*)d_in[5];
  const float* b0_0  = (const float*)d_in[6];
  const float* W1_0  = (const float*)d_in[7];
  const float* b1_0  = (const float*)d_in[8];
  const float* gW0   = (const float*)d_in[9];
  const float* gb0   = (const float*)d_in[10];
  const float* gW1   = (const float*)d_in[11];
  const float* gb1   = (const float*)d_in[12];
  const float* Wo    = (const float*)d_in[13];
  const float* bo    = (const float*)d_in[14];
  const float* A1    = (const float*)d_in[15];
  const float* a1    = (const float*)d_in[16];
  const float* A2    = (const float*)d_in[17];
  const float* a2    = (const float*)d_in[18];
  const float* A3    = (const float*)d_in[19];
  const float* a3    = (const float*)d_in[20];
  const float* A4    = (const float*)d_in[21];
  const float* a4    = (const float*)d_in[22];

  char* w = (char*)d_ws;
  const size_t SA = (size_t)Vpad * 256 * 2;
  _Float16* hA    = (_Float16*)(w);
  _Float16* outB  = (_Float16*)(w + SA);
  _Float16* nbrB  = (_Float16*)(w + 2*SA);
  _Float16* z1    = (_Float16*)(w + 3*SA);
  size_t off = 4 * SA;
  float*    P     = (float*)(w + off);    off += (size_t)4 * Vpad * 256 * 4;
  _Float16* WbT   = (_Float16*)(w + off); off += (size_t)256*3840*2;
  _Float16* convB = (_Float16*)(w + off); off += (size_t)10*131072*2;
  _Float16* A1T   = (_Float16*)(w + off); off += (size_t)131072*2;
  float*    vertW = (float*)(w + off);    off += (size_t)1536*4;
  int*      cnt   = (int*)(w + off);      off += (size_t)V*4;
  int*      adj   = (int*)(w + off);      // V*64*4

  hipMemsetAsync(cnt, 0, (size_t)V*4, stream);

  k_fill<<<dim3((E + 255)/256), dim3(256), 0, stream>>>(edges, E, cnt, adj);
  k_trans_bb<<<dim3(60, 4), dim3(256), 0, stream>>>(Wb, WbT);
  k_pack_frag<<<dim3(673), dim3(256), 0, stream>>>(
      W0_0, W1_0, gW0, gW1, A1, convB, A1T, vertW);

  // backbone split-K=4: P[z] = X @ Wb (slices), then reduce(+bias, relu)
  k_gemm_bb<<<dim3(161, 2, 4), dim3(256), 0, stream>>>(X, WbT, P, V, Vpad, F, F, 960);
  k_reduce<<<dim3(Vpad * 64 / 256), dim3(256), 0, stream>>>(P, bbias, hA, V, Vpad);

  for (int l = 0; l < 10; l++){
    const float* bp0 = l ? gb0 + (size_t)(l-1)*256 : b0_0;
    const float* bp1 = l ? gb1 + (size_t)(l-1)*256 : b1_0;
    const _Float16* Bt = convB + (size_t)l * 131072;
    if (l == 0)
      k_conv<false, true, true><<<dim3(161, 4), dim3(256), 0, stream>>>(
          hA, Bt, bp0, bp1, vertW, verts, outB, nbrB, V);
    else
      k_conv<false, true, false><<<dim3(161, 4), dim3(256), 0, stream>>>(
          hA, Bt, bp0, bp1, nullptr, nullptr, outB, nbrB, V);
    k_gather<<<dim3(5124), dim3(256), 0, stream>>>(outB, nbrB, cnt, adj, hA, V);
  }

  // z1 = relu(h @ A1 + a1)
  k_conv<true, false, false><<<dim3(161, 2), dim3(256), 0, stream>>>(
      hA, A1T, a1, nullptr, nullptr, nullptr, z1, nullptr, V);

  k_head<<<dim3(V/16), dim3(1024), 0, stream>>>(
      hA, z1, Wo, bo, A2, a2, A3, a3, A4, a4, (float*)d_out, V);
}

// Round 4
// 979.310 us; speedup vs baseline: 1.0928x; 1.0125x over previous
//
#include <hip/hip_runtime.h>

typedef _Float16 half8  __attribute__((ext_vector_type(8)));
typedef _Float16 half4v __attribute__((ext_vector_type(4)));
typedef float    floatx4 __attribute__((ext_vector_type(4)));

#define DEVINL __device__ __forceinline__

// async global->LDS, 16B per lane; LDS dest = wave-uniform base + lane*16
DEVINL void async_cp16(const void* g, void* l){
  __builtin_amdgcn_global_load_lds(
      (const __attribute__((address_space(1))) void*)g,
      (__attribute__((address_space(3))) void*)l,
      16, 0, 0);
}

DEVINL float wred64(float x){
  #pragma unroll
  for (int m = 32; m; m >>= 1) x += __shfl_xor(x, m, 64);
  return x;
}

// ---------------------------------------------------------------------------
// Backbone GEMM, split-K, BN folded: P[z] = A(f32 slice)@B(full 256 cols),
// f16 partials. 128m x 256n tile, BK=32, 4 waves 2x2 (wave = 64m x 128n).
// A f32 staged via global_load_lds, XOR unit swizzle (16B units, ^row&7);
// B f16 staged likewise (^row&3). X read exactly once from HBM.
// ---------------------------------------------------------------------------
__global__ __launch_bounds__(256, 2) void k_gemm_bb(
    const float* __restrict__ A, const _Float16* __restrict__ BT,
    _Float16* __restrict__ P, int M, int Mpad, int K, int lda, int kChunk)
{
  constexpr int BM = 128, BK = 32;
  __shared__ alignas(16) float    As[BM * BK];    // 16 KB
  __shared__ alignas(16) _Float16 Bs[256 * BK];   // 16 KB
  const int tid = threadIdx.x, wid = tid >> 6, lane = tid & 63;
  const int bm = blockIdx.x, bz = blockIdx.z;
  const int kbeg = bz * kChunk, kend = kbeg + kChunk;

  // A staging: 4 issues/wave, 8 rows x 8 units(16B); phys unit holds logical ^ (row&7)
  const float* aSrc[4]; float* aDst[4];
  const int uSwA = (lane & 7) ^ ((lane >> 3) & 7);
  #pragma unroll
  for (int c = 0; c < 4; c++){
    int rloc = wid * 32 + c * 8 + (lane >> 3);
    int r = min(bm * BM + rloc, M - 1);
    aSrc[c] = A + (size_t)r * lda + uSwA * 4;
    aDst[c] = &As[rloc * BK];
  }
  // B staging: 4 issues/wave, 16 rows x 4 units(16B); phys unit holds logical ^ (row&3)
  const _Float16* bSrc[4]; _Float16* bDst[4];
  const int uSwB = (lane & 3) ^ ((lane >> 2) & 3);
  #pragma unroll
  for (int s = 0; s < 4; s++){
    int rloc = wid * 64 + s * 16 + (lane >> 2);
    bSrc[s] = BT + (size_t)rloc * K + uSwB * 8;
    bDst[s] = &Bs[rloc * BK];
  }

  floatx4 acc[4][8];
  #pragma unroll
  for (int mt = 0; mt < 4; mt++)
    #pragma unroll
    for (int nt = 0; nt < 8; nt++) acc[mt][nt] = {0.f, 0.f, 0.f, 0.f};

  const int arow0 = (wid >> 1) * 64 + (lane & 15);
  const int g2 = (lane >> 4) * 2;
  const int a7 = lane & 7;
  const int brow0 = (wid & 1) * 128 + (lane & 15);
  const int ub0 = lane >> 4;

  for (int k0 = kbeg; k0 < kend; k0 += BK){
    __syncthreads();
    #pragma unroll
    for (int c = 0; c < 4; c++) async_cp16(aSrc[c] + k0, aDst[c]);
    #pragma unroll
    for (int s = 0; s < 4; s++) async_cp16(bSrc[s] + k0, bDst[s]);
    __syncthreads();
    half8 af[4], bf[8];
    #pragma unroll
    for (int mt = 0; mt < 4; mt++){
      int arow = arow0 + mt * 16;
      floatx4 lo = *(const floatx4*)&As[arow * BK + ((g2    ) ^ a7) * 4];
      floatx4 hi = *(const floatx4*)&As[arow * BK + ((g2 + 1) ^ a7) * 4];
      #pragma unroll
      for (int j = 0; j < 4; j++){ af[mt][j] = (_Float16)lo[j]; af[mt][4+j] = (_Float16)hi[j]; }
    }
    #pragma unroll
    for (int nt = 0; nt < 8; nt++){
      int brow = brow0 + nt * 16;
      bf[nt] = *(const half8*)&Bs[brow * BK + (ub0 ^ (brow & 3)) * 8];
    }
    #pragma unroll
    for (int mt = 0; mt < 4; mt++)
      #pragma unroll
      for (int nt = 0; nt < 8; nt++)
        acc[mt][nt] = __builtin_amdgcn_mfma_f32_16x16x32_f16(af[mt], bf[nt], acc[mt][nt], 0, 0, 0);
  }

  // C/D layout: col = lane&15, row = (lane>>4)*4 + i
  const int colLocal = (wid & 1) * 128 + (lane & 15);
  const int rowLocal = (wid >> 1) * 64 + (lane >> 4) * 4;
  _Float16* Pz = P + (size_t)bz * Mpad * 256;
  #pragma unroll
  for (int nt = 0; nt < 8; nt++){
    int col = colLocal + nt * 16;
    #pragma unroll
    for (int mt = 0; mt < 4; mt++){
      int r0 = bm * BM + rowLocal + mt * 16;
      #pragma unroll
      for (int i = 0; i < 4; i++)
        Pz[(size_t)(r0 + i) * 256 + col] = (_Float16)acc[mt][nt][i];
    }
  }
}

// ---------------------------------------------------------------------------
// Reduce split-K f16 partials: hA = relu(sum_z P[z] + bias); pad rows -> 0.
// ---------------------------------------------------------------------------
__global__ __launch_bounds__(256) void k_reduce(
    const _Float16* __restrict__ P, const float* __restrict__ bias,
    _Float16* __restrict__ hA, int V, int Mpad)
{
  int idx = blockIdx.x * 256 + threadIdx.x;  // 8-element group
  int base = idx * 8;
  int r = base >> 8, c = base & 255;
  const size_t stride = (size_t)Mpad * 256;
  const _Float16* p = P + (size_t)base;
  half8 s0 = *(const half8*)(p);
  half8 s1 = *(const half8*)(p + stride);
  half8 s2 = *(const half8*)(p + 2 * stride);
  half8 s3 = *(const half8*)(p + 3 * stride);
  half8 o;
  if (r < V){
    #pragma unroll
    for (int e = 0; e < 8; e++){
      float v = (float)s0[e] + (float)s1[e] + (float)s2[e] + (float)s3[e] + bias[c + e];
      o[e] = (_Float16)fmaxf(v, 0.f);
    }
  } else {
    #pragma unroll
    for (int e = 0; e < 8; e++) o[e] = (_Float16)0.f;
  }
  *(half8*)(hA + (size_t)base) = o;
}

// ---------------------------------------------------------------------------
// Conv/z1 GEMM: barrier-free streamer. Weights pre-packed in MFMA fragment
// order: frag row r = n16*8 + j, element (lane,e): n = n16*16+(lane&15),
// k = j*32+(lane>>4)*8+e. Block: 128m x 128n, B tile 64KB staged once.
// ---------------------------------------------------------------------------
template<bool RELU, bool SPLIT, bool VERTC>
__global__ __launch_bounds__(256) void k_conv(
    const _Float16* __restrict__ A,       // Mpad x 256
    const _Float16* __restrict__ BTfrag,  // fragment-packed base
    const float* __restrict__ bias0, const float* __restrict__ bias1,
    const float* __restrict__ vertW, const float* __restrict__ verts,
    _Float16* __restrict__ C0, _Float16* __restrict__ C1, int Vreal)
{
  __shared__ alignas(16) _Float16 Bs[32768];  // 64 KB
  const int tid = threadIdx.x, wid = tid >> 6, lane = tid & 63;
  const int bm = blockIdx.x, bn = blockIdx.y;

  const _Float16* src = BTfrag + (size_t)bn * 32768;
  #pragma unroll
  for (int jj = 0; jj < 16; jj++){
    int e = (jj * 256 + tid) * 8;
    *(half8*)&Bs[e] = *(const half8*)&src[e];
  }
  __syncthreads();

  const _Float16* Arow[4];
  #pragma unroll
  for (int mt = 0; mt < 4; mt++)
    Arow[mt] = A + (size_t)(bm * 128 + (wid >> 1) * 64 + mt * 16 + (lane & 15)) * 256
                 + (lane >> 4) * 8;
  const int nbase = (wid & 1) * 4;

  floatx4 acc[4][4];
  #pragma unroll
  for (int mt = 0; mt < 4; mt++)
    #pragma unroll
    for (int nt = 0; nt < 4; nt++) acc[mt][nt] = {0.f, 0.f, 0.f, 0.f};

  #pragma unroll
  for (int j = 0; j < 8; j++){
    half8 af[4], bf[4];
    #pragma unroll
    for (int mt = 0; mt < 4; mt++) af[mt] = *(const half8*)(Arow[mt] + j * 32);
    #pragma unroll
    for (int nt = 0; nt < 4; nt++)
      bf[nt] = *(const half8*)&Bs[(((nbase + nt) * 8 + j) * 64 + lane) * 8];
    #pragma unroll
    for (int mt = 0; mt < 4; mt++)
      #pragma unroll
      for (int nt = 0; nt < 4; nt++)
        acc[mt][nt] = __builtin_amdgcn_mfma_f32_16x16x32_f16(af[mt], bf[nt], acc[mt][nt], 0, 0, 0);
  }

  const int colLocal = (wid & 1) * 64 + (lane & 15);
  const int rowLocal = (wid >> 1) * 64 + (lane >> 4) * 4;
  #pragma unroll
  for (int nt = 0; nt < 4; nt++){
    int g = bn * 128 + colLocal + nt * 16;
    _Float16* Cp = C0;
    const float* bp = bias0;
    int col = g;
    if (SPLIT && g >= 256){ Cp = C1; bp = bias1; col = g - 256; }
    float b = bp[col];
    float w0 = 0.f, w1 = 0.f, w2 = 0.f;
    if (VERTC){ w0 = vertW[g*3+0]; w1 = vertW[g*3+1]; w2 = vertW[g*3+2]; }
    #pragma unroll
    for (int mt = 0; mt < 4; mt++){
      int r0 = bm * 128 + rowLocal + mt * 16;
      #pragma unroll
      for (int i = 0; i < 4; i++){
        int r = r0 + i;
        float v = acc[mt][nt][i] + b;
        if (VERTC){
          int vr = min(r, Vreal - 1);
          v += verts[vr*3+0] * w0 + verts[vr*3+1] * w1 + verts[vr*3+2] * w2;
        }
        if (RELU) v = fmaxf(v, 0.f);
        Cp[(size_t)r * 256 + col] = (_Float16)v;
      }
    }
  }
}

// ---------------------------------------------------------------------------
__global__ __launch_bounds__(256) void k_fill(const int* __restrict__ e, int E,
                                              int* __restrict__ cnt, int* __restrict__ adj){
  int t = blockIdx.x * 256 + threadIdx.x;
  if (t >= E) return;
  int i = e[t*2], j = e[t*2+1];
  int s = atomicAdd(&cnt[i], 1); if (s < 64) adj[(size_t)i*64 + s] = j;
  int q = atomicAdd(&cnt[j], 1); if (q < 64) adj[(size_t)j*64 + q] = i;
}

// ---------------------------------------------------------------------------
// WbT transpose (f32 KxN -> f16 NxK) via LDS 64x64 tiles.
// ---------------------------------------------------------------------------
__global__ __launch_bounds__(256) void k_trans_bb(
    const float* __restrict__ Wb, _Float16* __restrict__ WbT)
{
  __shared__ float T[64][65];
  const int k0 = blockIdx.x * 64, n0 = blockIdx.y * 64;
  const int tr = threadIdx.x >> 6, tc = threadIdx.x & 63;
  #pragma unroll
  for (int i = 0; i < 16; i++){
    int rr = i * 4 + tr;
    T[rr][tc] = Wb[(size_t)(k0 + rr) * 256 + n0 + tc];
  }
  __syncthreads();
  #pragma unroll
  for (int i = 0; i < 16; i++){
    int rr = i * 4 + tr;
    WbT[(size_t)(n0 + rr) * 3840 + k0 + tc] = (_Float16)T[tc][rr];
  }
}

// ---------------------------------------------------------------------------
// Coalesced fragment packer: block = one 64k x 256n tile of one matrix.
// Load coalesced f32 rows into LDS (stride 257: column reads 2-way = free),
// write frag rows as coalesced half8. 21 matrices x 4 k-tiles = 84 blocks,
// block 84 = vertW tail.
// ---------------------------------------------------------------------------
__global__ __launch_bounds__(256) void k_pack2(
    const float* __restrict__ W0_0, const float* __restrict__ W1_0,
    const float* __restrict__ gW0,  const float* __restrict__ gW1,
    const float* __restrict__ A1,
    _Float16* __restrict__ convB, _Float16* __restrict__ A1T,
    float* __restrict__ vertW)
{
  __shared__ float T[64 * 257];
  const int b = blockIdx.x;
  if (b == 84){
    for (int i = threadIdx.x; i < 1536; i += 256){
      int n = i / 3, c = i % 3;
      vertW[i] = (n < 256) ? W0_0[(size_t)(256 + c) * 256 + n]
                           : W1_0[(size_t)(256 + c) * 256 + (n - 256)];
    }
    return;
  }
  const int m = b >> 2, t = b & 3;
  const float* W; _Float16* dstBase; int rAdd;
  if (m == 20){ W = A1; dstBase = A1T; rAdd = 0; }
  else {
    int L = m >> 1, hsel = m & 1;
    W = hsel ? (L ? gW1 + (size_t)(L-1)*65536 : W1_0)
             : (L ? gW0 + (size_t)(L-1)*65536 : W0_0);
    dstBase = convB + (size_t)L * 131072;
    rAdd = hsel * 128;
  }
  const int k0 = t * 64;
  const int tr = threadIdx.x >> 6, tc = (threadIdx.x & 63) * 4;
  #pragma unroll
  for (int i = 0; i < 16; i++){
    int rr = i * 4 + tr;
    floatx4 v = *(const floatx4*)&W[(size_t)(k0 + rr) * 256 + tc];
    T[rr * 257 + tc + 0] = v[0]; T[rr * 257 + tc + 1] = v[1];
    T[rr * 257 + tc + 2] = v[2]; T[rr * 257 + tc + 3] = v[3];
  }
  __syncthreads();
  const int wid = threadIdx.x >> 6, lane = threadIdx.x & 63;
  #pragma unroll
  for (int q = 0; q < 8; q++){
    int n16 = wid * 4 + (q >> 1);
    int jj  = q & 1;
    int r = rAdd + n16 * 8 + (t * 2 + jj);
    int kk = jj * 32 + (lane >> 4) * 8;
    int n  = n16 * 16 + (lane & 15);
    half8 v;
    #pragma unroll
    for (int e = 0; e < 8; e++) v[e] = (_Float16)T[(kk + e) * 257 + n];
    *(half8*)&dstBase[(size_t)r * 512 + lane * 8] = v;
  }
}

// ---------------------------------------------------------------------------
// Gather: h[v] = relu(out[v] + sum_{u in adj[v]} nbr[u]); one wave per vertex.
// ---------------------------------------------------------------------------
__global__ __launch_bounds__(256) void k_gather(
    const _Float16* __restrict__ outB, const _Float16* __restrict__ nbrB,
    const int* __restrict__ cnt, const int* __restrict__ adj,
    _Float16* __restrict__ h, int V)
{
  int gw = (int)((blockIdx.x * 256 + threadIdx.x) >> 6);
  int lane = threadIdx.x & 63;
  if (gw >= V) return;
  half4v o = ((const half4v*)(outB + (size_t)gw * 256))[lane];
  float a0 = (float)o[0], a1 = (float)o[1], a2 = (float)o[2], a3 = (float)o[3];
  int n = min(cnt[gw], 64);
  const int* ap = adj + (size_t)gw * 64;
  int d = 0;
  for (; d + 1 < n; d += 2){
    int u0 = ap[d], u1 = ap[d+1];
    half4v x = ((const half4v*)(nbrB + (size_t)u0 * 256))[lane];
    half4v y = ((const half4v*)(nbrB + (size_t)u1 * 256))[lane];
    a0 += (float)x[0] + (float)y[0]; a1 += (float)x[1] + (float)y[1];
    a2 += (float)x[2] + (float)y[2]; a3 += (float)x[3] + (float)y[3];
  }
  if (d < n){
    int u = ap[d];
    half4v x = ((const half4v*)(nbrB + (size_t)u * 256))[lane];
    a0 += (float)x[0]; a1 += (float)x[1]; a2 += (float)x[2]; a3 += (float)x[3];
  }
  half4v rr;
  rr[0] = (_Float16)fmaxf(a0, 0.f); rr[1] = (_Float16)fmaxf(a1, 0.f);
  rr[2] = (_Float16)fmaxf(a2, 0.f); rr[3] = (_Float16)fmaxf(a3, 0.f);
  ((half4v*)(h + (size_t)gw * 256))[lane] = rr;
}

// ---------------------------------------------------------------------------
// Head: delta_v = h@Wo+bo ; conf = sigmoid(relu(relu(z1@A2+a2)@A3+a3)@A4+a4)
// ---------------------------------------------------------------------------
__global__ __launch_bounds__(1024) void k_head(
    const _Float16* __restrict__ hA, const _Float16* __restrict__ z1,
    const float* __restrict__ Wo, const float* __restrict__ bo,
    const float* __restrict__ A2, const float* __restrict__ a2,
    const float* __restrict__ A3, const float* __restrict__ a3,
    const float* __restrict__ A4, const float* __restrict__ a4,
    float* __restrict__ dOut, int V)
{
  __shared__ float A2s[256 * 64];
  __shared__ float A3s[64 * 32];
  __shared__ float Wos[768];
  __shared__ float zrow[16][256];
  __shared__ float z2s[16][64];
  const int tid = threadIdx.x;
  for (int i = tid; i < 256*64; i += 1024) A2s[i] = A2[i];
  for (int i = tid; i < 64*32;  i += 1024) A3s[i] = A3[i];
  if (tid < 768) Wos[tid] = Wo[tid];
  __syncthreads();
  const int wid = tid >> 6, lane = tid & 63;
  const int v = blockIdx.x * 16 + wid;
  if (v >= V) return;

  half4v hv = ((const half4v*)(hA + (size_t)v * 256))[lane];
  float hf[4] = { (float)hv[0], (float)hv[1], (float)hv[2], (float)hv[3] };
  float p0 = 0.f, p1 = 0.f, p2 = 0.f;
  int c0 = lane * 4;
  #pragma unroll
  for (int j = 0; j < 4; j++){
    p0 += hf[j] * Wos[(c0+j)*3 + 0];
    p1 += hf[j] * Wos[(c0+j)*3 + 1];
    p2 += hf[j] * Wos[(c0+j)*3 + 2];
  }
  p0 = wred64(p0); p1 = wred64(p1); p2 = wred64(p2);
  if (lane == 0){
    dOut[(size_t)v*3 + 0] = p0 + bo[0];
    dOut[(size_t)v*3 + 1] = p1 + bo[1];
    dOut[(size_t)v*3 + 2] = p2 + bo[2];
  }

  half4v zv = ((const half4v*)(z1 + (size_t)v * 256))[lane];
  floatx4 zf; zf[0] = (float)zv[0]; zf[1] = (float)zv[1]; zf[2] = (float)zv[2]; zf[3] = (float)zv[3];
  ((floatx4*)zrow[wid])[lane] = zf;
  __threadfence_block();
  float acc2 = a2[lane];
  #pragma unroll 4
  for (int c = 0; c < 256; c++) acc2 += zrow[wid][c] * A2s[c*64 + lane];
  acc2 = fmaxf(acc2, 0.f);
  z2s[wid][lane] = acc2;
  __threadfence_block();
  int o = lane & 31;
  float acc3 = a3[o];
  #pragma unroll 4
  for (int c = 0; c < 64; c++) acc3 += z2s[wid][c] * A3s[c*32 + o];
  acc3 = fmaxf(acc3, 0.f);
  float p = (lane < 32) ? acc3 * A4[lane] : 0.f;
  p = wred64(p);
  if (lane == 0){
    float s = 1.f / (1.f + expf(-(p + a4[0])));
    dOut[(size_t)V*3 + v] = s;
  }
}

// ---------------------------------------------------------------------------
extern "C" void kernel_launch(void* const* d_in, const int* in_sizes, int n_in,
                              void* d_out, int out_size, void* d_ws, size_t ws_size,
                              hipStream_t stream)
{
  const int V = 20496, E = 61440, F = 3840, Vpad = 20608; // 161*128
  const float* X     = (const float*)d_in[0];
  const float* verts = (const float*)d_in[1];
  const int*   edges = (const int*)d_in[2];
  const float* Wb    = (const float*)d_in[3];
  const float* bbias = (const float*)d_in[4];
  const float* W0_0  = (const float*)d_in[5];
  const float* b0_0  = (const float*)d_in[6];
  const float* W1_0  = (const float*)d_in[7];
  const float* b1_0  = (const float*)d_in[8];
  const float* gW0   = (const float*)d_in[9];
  const float* gb0   = (const float*)d_in[10];
  const float* gW1   = (const float*)d_in[11];
  const float* gb1   = (const float*)d_in[12];
  const float* Wo    = (const float*)d_in[13];
  const float* bo    = (const float*)d_in[14];
  const float* A1    = (const float*)d_in[15];
  const float* a1    = (const float*)d_in[16];
  const float* A2    = (const float*)d_in[17];
  const float* a2    = (const float*)d_in[18];
  const float* A3    = (const float*)d_in[19];
  const float* a3    = (const float*)d_in[20];
  const float* A4    = (const float*)d_in[21];
  const float* a4    = (const float*)d_in[22];

  char* w = (char*)d_ws;
  const size_t SA = (size_t)Vpad * 256 * 2;
  _Float16* hA    = (_Float16*)(w);
  _Float16* outB  = (_Float16*)(w + SA);
  _Float16* nbrB  = (_Float16*)(w + 2*SA);
  _Float16* z1    = (_Float16*)(w + 3*SA);
  size_t off = 4 * SA;
  _Float16* P     = (_Float16*)(w + off); off += (size_t)4 * Vpad * 256 * 2;
  _Float16* WbT   = (_Float16*)(w + off); off += (size_t)256*3840*2;
  _Float16* convB = (_Float16*)(w + off); off += (size_t)10*131072*2;
  _Float16* A1T   = (_Float16*)(w + off); off += (size_t)131072*2;
  float*    vertW = (float*)(w + off);    off += (size_t)1536*4;
  int*      cnt   = (int*)(w + off);      off += (size_t)V*4;
  int*      adj   = (int*)(w + off);      // V*64*4

  hipMemsetAsync(cnt, 0, (size_t)V*4, stream);

  k_fill<<<dim3((E + 255)/256), dim3(256), 0, stream>>>(edges, E, cnt, adj);
  k_trans_bb<<<dim3(60, 4), dim3(256), 0, stream>>>(Wb, WbT);
  k_pack2<<<dim3(85), dim3(256), 0, stream>>>(
      W0_0, W1_0, gW0, gW1, A1, convB, A1T, vertW);

  // backbone split-K=4, BN folded: P[z] = X @ Wb slices; reduce(+bias, relu)
  k_gemm_bb<<<dim3(161, 1, 4), dim3(256), 0, stream>>>(X, WbT, P, V, Vpad, F, F, 960);
  k_reduce<<<dim3(Vpad / 8), dim3(256), 0, stream>>>(P, bbias, hA, V, Vpad);

  for (int l = 0; l < 10; l++){
    const float* bp0 = l ? gb0 + (size_t)(l-1)*256 : b0_0;
    const float* bp1 = l ? gb1 + (size_t)(l-1)*256 : b1_0;
    const _Float16* Bt = convB + (size_t)l * 131072;
    if (l == 0)
      k_conv<false, true, true><<<dim3(161, 4), dim3(256), 0, stream>>>(
          hA, Bt, bp0, bp1, vertW, verts, outB, nbrB, V);
    else
      k_conv<false, true, false><<<dim3(161, 4), dim3(256), 0, stream>>>(
          hA, Bt, bp0, bp1, nullptr, nullptr, outB, nbrB, V);
    k_gather<<<dim3(5124), dim3(256), 0, stream>>>(outB, nbrB, cnt, adj, hA, V);
  }

  // z1 = relu(h @ A1 + a1)
  k_conv<true, false, false><<<dim3(161, 2), dim3(256), 0, stream>>>(
      hA, A1T, a1, nullptr, nullptr, nullptr, z1, nullptr, V);

  k_head<<<dim3(V/16), dim3(1024), 0, stream>>>(
      hA, z1, Wo, bo, A2, a2, A3, a3, A4, a4, (float*)d_out, V);
}